// Round 7
// baseline (665.009 us; speedup 1.0000x reference)
//
#include <hip/hip_runtime.h>
#include <hip/hip_bf16.h>

// GCN 2-layer: h1 = relu(GCNConv(x, W1, b1)); out = log_softmax(GCNConv(h1, W2, b2))
// GCNConv(h)[d] = dinv[d] * ( sum_{s->d} (h@W)[s]*dinv[s] + (h@W)[d]*dinv[d] ) + b
//
// Round-7: per-bucket LDS accumulation replaces CSR gather (kills col/row_start/
// bucket_csr fill + row-loop divergence); h1s/h2s stored bf16 (halves gather
// traffic). r6 top dispatch was the harness ws-poison fill (44us, fixed cost).
// Dtypes (validated r0-r6): fp32 in/out, int32 edges; flags = runtime hedge.

#define FEAT_IN 64
#define FEAT_H  32
#define FEAT_O  16
#define BUCK    128   // nodes per bucket
#define MAXNB   1024  // max buckets (n <= 131072; n < 2^24 for packing)
#define PART_G  192   // histogram/partition blocks

__device__ __forceinline__ float2 upk_bf2(unsigned w) {
    return make_float2(__uint_as_float(w << 16), __uint_as_float(w & 0xFFFF0000u));
}

__global__ void k_detect(const uint4* __restrict__ xw4,
                         const int* __restrict__ ei, int* __restrict__ flags) {
    __shared__ int s_f32, s_i64nz;
    if (threadIdx.x == 0) { s_f32 = 0; s_i64nz = 0; }
    __syncthreads();
    int t = threadIdx.x;
    int hit = 0;
    for (int i = t; i < 4096; i += 256) {
        uint4 u = xw4[i];
        unsigned a0 = u.x, a1 = u.y, a2 = u.z, a3 = u.w;
        if ((a0 & 0x7F800000u) == 0x7F800000u || (a0 & 0x00007F80u) == 0x00007F80u) hit = 1;
        if ((a1 & 0x7F800000u) == 0x7F800000u || (a1 & 0x00007F80u) == 0x00007F80u) hit = 1;
        if ((a2 & 0x7F800000u) == 0x7F800000u || (a2 & 0x00007F80u) == 0x00007F80u) hit = 1;
        if ((a3 & 0x7F800000u) == 0x7F800000u || (a3 & 0x00007F80u) == 0x00007F80u) hit = 1;
    }
    if (hit) atomicOr(&s_f32, 1);
    int nz = 0;
    for (int i = t; i < 128; i += 256) {
        if (ei[2 * i + 1] != 0) nz = 1;  // int32 edges: odd words random nonzero
    }
    if (nz) atomicOr(&s_i64nz, 1);
    __syncthreads();
    if (t == 0) { flags[0] = s_f32; flags[1] = s_i64nz ? 0 : 1; }
}

// ---- pass 1: per-block bucket histogram -> hist[b*G + g] ----
__global__ void k_hist(const int* __restrict__ ei, int e, const int* __restrict__ flags,
                       int* __restrict__ hist, int G, int NBk) {
    __shared__ int lh[MAXNB];
    int t = threadIdx.x, g = blockIdx.x;
    for (int i = t; i < NBk; i += 256) lh[i] = 0;
    __syncthreads();
    int chunk = (e + G - 1) / G;
    int beg = g * chunk, end = min(e, beg + chunk);
    bool i64 = flags[1] != 0;
    for (int i = beg + t; i < end; i += 256) {
        int d = i64 ? ei[2 * (e + i)] : ei[e + i];
        atomicAdd(&lh[d >> 7], 1);
    }
    __syncthreads();
    for (int i = t; i < NBk; i += 256) hist[(size_t)i * G + g] = lh[i];
}

// ---- exclusive scan (len <= 262144); final value = out[i] + bsum[i>>10] ----
__global__ void k_scan1(const int* __restrict__ in, int* __restrict__ out,
                        int* __restrict__ bsum, int len) {
    __shared__ int s[256];
    int t = threadIdx.x;
    int base = blockIdx.x * 1024 + t * 4;
    int a0 = (base + 0) < len ? in[base + 0] : 0;
    int a1 = (base + 1) < len ? in[base + 1] : 0;
    int a2 = (base + 2) < len ? in[base + 2] : 0;
    int a3 = (base + 3) < len ? in[base + 3] : 0;
    int tsum = a0 + a1 + a2 + a3;
    s[t] = tsum;
    __syncthreads();
    for (int off = 1; off < 256; off <<= 1) {
        int x = (t >= off) ? s[t - off] : 0;
        __syncthreads();
        s[t] += x;
        __syncthreads();
    }
    int ex = s[t] - tsum;
    if (base + 0 < len) out[base + 0] = ex;
    if (base + 1 < len) out[base + 1] = ex + a0;
    if (base + 2 < len) out[base + 2] = ex + a0 + a1;
    if (base + 3 < len) out[base + 3] = ex + a0 + a1 + a2;
    if (t == 255) bsum[blockIdx.x] = s[255];
}

__global__ void k_scan2(int* __restrict__ bsum, int nb) {  // nb <= 256
    __shared__ int s[256];
    int t = threadIdx.x;
    int v = (t < nb) ? bsum[t] : 0;
    s[t] = v;
    __syncthreads();
    for (int off = 1; off < 256; off <<= 1) {
        int x = (t >= off) ? s[t - off] : 0;
        __syncthreads();
        s[t] += x;
        __syncthreads();
    }
    if (t < nb) bsum[t] = s[t] - v;
}

__device__ __forceinline__ int base_at(const int* base, const int* bsum, int idx) {
    return base[idx] + bsum[idx >> 10];
}

// ---- pass 2: scatter packed (src | dlow<<24) into bucket-ordered part[] ----
__global__ void k_partition(const int* __restrict__ ei, int e, const int* __restrict__ flags,
                            const int* __restrict__ base, const int* __restrict__ bsum,
                            int* __restrict__ part, int G, int NBk) {
    __shared__ int cur[MAXNB];
    int t = threadIdx.x, g = blockIdx.x;
    for (int i = t; i < NBk; i += 256) cur[i] = base_at(base, bsum, i * G + g);
    __syncthreads();
    int chunk = (e + G - 1) / G;
    int beg = g * chunk, end = min(e, beg + chunk);
    bool i64 = flags[1] != 0;
    for (int i = beg + t; i < end; i += 256) {
        int s, d;
        if (i64) { s = ei[2 * i]; d = ei[2 * (e + i)]; }
        else     { s = ei[i];     d = ei[e + i]; }
        int pos = atomicAdd(&cur[d >> 7], 1);
        part[pos] = s | ((d & (BUCK - 1)) << 24);
    }
}

// ---- per-bucket degree -> dinv ----
__global__ void k_bucket_dinv(const int* __restrict__ part, const int* __restrict__ base,
                              const int* __restrict__ bsum, int e, int G, int NBk, int n,
                              float* __restrict__ dinv) {
    __shared__ int cnt[BUCK];
    int t = threadIdx.x, b = blockIdx.x;
    if (t < BUCK) cnt[t] = 0;
    __syncthreads();
    int beg = base_at(base, bsum, b * G);
    int end = (b == NBk - 1) ? e : base_at(base, bsum, (b + 1) * G);
    for (int j = beg + t; j < end; j += 256) atomicAdd(&cnt[((unsigned)part[j]) >> 24], 1);
    __syncthreads();
    if (t < BUCK) {
        int node = b * BUCK + t;
        if (node < n) dinv[node] = rsqrtf((float)cnt[t] + 1.0f);  // +1 self-loop
    }
}

// ---- layer 1 GEMM: h1s(bf16) = (x @ W1) * dinv ; 32 nodes/block ----
__global__ void k_gemm1(const void* __restrict__ xv, const void* __restrict__ W1v,
                        const int* __restrict__ flags, const float* __restrict__ dinv,
                        __hip_bfloat162* __restrict__ h1s2, int n) {
    __shared__ float sW[FEAT_IN * FEAT_H];   // 8 KB
    __shared__ float sx[16][FEAT_IN + 1];    // pad breaks nl-bank aliasing
    int t = threadIdx.x;
    bool f32 = flags[0] != 0;
    if (f32) {
        const float* W = (const float*)W1v;
        for (int i = t; i < FEAT_IN * FEAT_H; i += 256) sW[i] = W[i];
    } else {
        const __hip_bfloat16* W = (const __hip_bfloat16*)W1v;
        for (int i = t; i < FEAT_IN * FEAT_H; i += 256) sW[i] = __bfloat162float(W[i]);
    }
#pragma unroll
    for (int tile = 0; tile < 2; ++tile) {
        int nodeBase = blockIdx.x * 32 + tile * 16;
        __syncthreads();
        {   // stage 16 nodes of x
            int xn = t >> 4, c = t & 15;
            int node = nodeBase + xn;
            if (node < n) {
                if (f32) {
                    float4 v = ((const float4*)xv)[(size_t)node * 16 + c];
                    sx[xn][c * 4 + 0] = v.x; sx[xn][c * 4 + 1] = v.y;
                    sx[xn][c * 4 + 2] = v.z; sx[xn][c * 4 + 3] = v.w;
                } else {
                    const __hip_bfloat162* x2 = (const __hip_bfloat162*)xv;
                    float2 a = __bfloat1622float2(x2[(size_t)node * 32 + c * 2 + 0]);
                    float2 b = __bfloat1622float2(x2[(size_t)node * 32 + c * 2 + 1]);
                    sx[xn][c * 4 + 0] = a.x; sx[xn][c * 4 + 1] = a.y;
                    sx[xn][c * 4 + 2] = b.x; sx[xn][c * 4 + 3] = b.y;
                }
            }
        }
        __syncthreads();
        int nl = t >> 4, g = t & 15;
        int node = nodeBase + nl;
        if (node < n) {
            float a0 = 0.0f, a1 = 0.0f;
#pragma unroll
            for (int k = 0; k < FEAT_IN; ++k) {
                float s = sx[nl][k];
                a0 += s * sW[k * FEAT_H + 2 * g];
                a1 += s * sW[k * FEAT_H + 2 * g + 1];
            }
            float dv = dinv[node];
            __hip_bfloat162 o;
            o.x = __float2bfloat16(a0 * dv);
            o.y = __float2bfloat16(a1 * dv);
            h1s2[(size_t)node * 16 + g] = o;
        }
    }
}

// ---- layer-1 aggregate (LDS acc) + relu/bias + GEMM2 -> h2s(bf16) ----
__global__ void k_agg1(const int* __restrict__ part, const int* __restrict__ base,
                       const int* __restrict__ bsum, int e, int G, int NBk, int n,
                       const uint4* __restrict__ h1s4, const void* __restrict__ W2v,
                       const void* __restrict__ b1v, const int* __restrict__ flags,
                       const float* __restrict__ dinv, __hip_bfloat162* __restrict__ h2s2) {
    __shared__ float sW[FEAT_H * FEAT_O];
    __shared__ float sb1[FEAT_H];
    __shared__ float acc[FEAT_H][BUCK];   // 16 KB, bank = dl%32
    int t = threadIdx.x, b = blockIdx.x;
    bool f32 = flags[0] != 0;
    if (f32) {
        const float* W = (const float*)W2v;
        for (int i = t; i < FEAT_H * FEAT_O; i += 256) sW[i] = W[i];
        if (t < FEAT_H) sb1[t] = ((const float*)b1v)[t];
    } else {
        const __hip_bfloat16* W = (const __hip_bfloat16*)W2v;
        for (int i = t; i < FEAT_H * FEAT_O; i += 256) sW[i] = __bfloat162float(W[i]);
        if (t < FEAT_H) sb1[t] = __bfloat162float(((const __hip_bfloat16*)b1v)[t]);
    }
    int nb0 = b * BUCK;
    // init acc with self-loop rows (h1s already carries dinv[s])
    for (int idx = t; idx < BUCK * 4; idx += 256) {
        int nl = idx >> 2, c = idx & 3;
        int node = nb0 + nl;
        float2 p0, p1, p2, p3;
        if (node < n) {
            uint4 u = h1s4[(size_t)node * 4 + c];
            p0 = upk_bf2(u.x); p1 = upk_bf2(u.y); p2 = upk_bf2(u.z); p3 = upk_bf2(u.w);
        } else {
            p0 = p1 = p2 = p3 = make_float2(0.f, 0.f);
        }
        int fb = c * 8;
        acc[fb + 0][nl] = p0.x; acc[fb + 1][nl] = p0.y;
        acc[fb + 2][nl] = p1.x; acc[fb + 3][nl] = p1.y;
        acc[fb + 4][nl] = p2.x; acc[fb + 5][nl] = p2.y;
        acc[fb + 6][nl] = p3.x; acc[fb + 7][nl] = p3.y;
    }
    __syncthreads();
    int beg = base_at(base, bsum, b * G);
    int end = (b == NBk - 1) ? e : base_at(base, bsum, (b + 1) * G);
    int q = t & 3, eo = t >> 2;     // 4 lanes/edge, 64 edges in flight
    for (int j = beg + eo; j < end; j += 64) {
        int r = part[j];
        int s = r & 0x00FFFFFF, dl = ((unsigned)r) >> 24;
        uint4 u = h1s4[(size_t)s * 4 + q];
        float2 p0 = upk_bf2(u.x), p1 = upk_bf2(u.y), p2 = upk_bf2(u.z), p3 = upk_bf2(u.w);
        int fb = q * 8;
        atomicAdd(&acc[fb + 0][dl], p0.x); atomicAdd(&acc[fb + 1][dl], p0.y);
        atomicAdd(&acc[fb + 2][dl], p1.x); atomicAdd(&acc[fb + 3][dl], p1.y);
        atomicAdd(&acc[fb + 4][dl], p2.x); atomicAdd(&acc[fb + 5][dl], p2.y);
        atomicAdd(&acc[fb + 6][dl], p3.x); atomicAdd(&acc[fb + 7][dl], p3.y);
    }
    __syncthreads();
    // phase 2: h2 = (relu(dinv*acc + b1) @ W2) * dinv, bf16 store
#pragma unroll
    for (int sub = 0; sub < 4; ++sub) {
        int nl = (t >> 3) + sub * 32;
        int m = t & 7;
        int node = nb0 + nl;
        if (node < n) {
            float dv = dinv[node];
            float a0 = 0.0f, a1 = 0.0f;
#pragma unroll
            for (int f = 0; f < FEAT_H; ++f) {
                float z = fmaxf(dv * acc[f][nl] + sb1[f], 0.0f);
                a0 += z * sW[f * FEAT_O + 2 * m];
                a1 += z * sW[f * FEAT_O + 2 * m + 1];
            }
            __hip_bfloat162 o;
            o.x = __float2bfloat16(a0 * dv);
            o.y = __float2bfloat16(a1 * dv);
            h2s2[(size_t)node * 8 + m] = o;
        }
    }
}

// ---- layer-2 aggregate (LDS acc) + bias + log_softmax -> out(fp32) ----
__global__ void k_agg2(const int* __restrict__ part, const int* __restrict__ base,
                       const int* __restrict__ bsum, int e, int G, int NBk, int n,
                       const uint4* __restrict__ h2s4, const void* __restrict__ b2v,
                       const int* __restrict__ flags, const float* __restrict__ dinv,
                       float4* __restrict__ out4) {
    __shared__ float sb2[FEAT_O];
    __shared__ float acc[FEAT_O][BUCK];   // 8 KB
    int t = threadIdx.x, b = blockIdx.x;
    if (t < FEAT_O) {
        sb2[t] = flags[0] ? ((const float*)b2v)[t]
                          : __bfloat162float(((const __hip_bfloat16*)b2v)[t]);
    }
    int nb0 = b * BUCK;
    for (int idx = t; idx < BUCK * 2; idx += 256) {
        int nl = idx >> 1, c = idx & 1;
        int node = nb0 + nl;
        float2 p0, p1, p2, p3;
        if (node < n) {
            uint4 u = h2s4[(size_t)node * 2 + c];
            p0 = upk_bf2(u.x); p1 = upk_bf2(u.y); p2 = upk_bf2(u.z); p3 = upk_bf2(u.w);
        } else {
            p0 = p1 = p2 = p3 = make_float2(0.f, 0.f);
        }
        int fb = c * 8;
        acc[fb + 0][nl] = p0.x; acc[fb + 1][nl] = p0.y;
        acc[fb + 2][nl] = p1.x; acc[fb + 3][nl] = p1.y;
        acc[fb + 4][nl] = p2.x; acc[fb + 5][nl] = p2.y;
        acc[fb + 6][nl] = p3.x; acc[fb + 7][nl] = p3.y;
    }
    __syncthreads();
    int beg = base_at(base, bsum, b * G);
    int end = (b == NBk - 1) ? e : base_at(base, bsum, (b + 1) * G);
    int half = t & 1, eo = t >> 1;   // 2 lanes/edge, 128 edges in flight
    for (int j = beg + eo; j < end; j += 128) {
        int r = part[j];
        int s = r & 0x00FFFFFF, dl = ((unsigned)r) >> 24;
        uint4 u = h2s4[(size_t)s * 2 + half];
        float2 p0 = upk_bf2(u.x), p1 = upk_bf2(u.y), p2 = upk_bf2(u.z), p3 = upk_bf2(u.w);
        int fb = half * 8;
        atomicAdd(&acc[fb + 0][dl], p0.x); atomicAdd(&acc[fb + 1][dl], p0.y);
        atomicAdd(&acc[fb + 2][dl], p1.x); atomicAdd(&acc[fb + 3][dl], p1.y);
        atomicAdd(&acc[fb + 4][dl], p2.x); atomicAdd(&acc[fb + 5][dl], p2.y);
        atomicAdd(&acc[fb + 6][dl], p3.x); atomicAdd(&acc[fb + 7][dl], p3.y);
    }
    __syncthreads();
    // phase 2: 256 thr = 128 nodes x 2 halves; log_softmax over 16 feats
    {
        int nl = t >> 1, h = t & 1;
        int node = nb0 + nl;
        if (node < n) {
            float dv = dinv[node];
            float v[8];
            float mx = -1e30f;
#pragma unroll
            for (int k = 0; k < 8; ++k) {
                v[k] = dv * acc[h * 8 + k][nl] + sb2[h * 8 + k];
                mx = fmaxf(mx, v[k]);
            }
            mx = fmaxf(mx, __shfl_xor(mx, 1));
            float ssum = 0.0f;
#pragma unroll
            for (int k = 0; k < 8; ++k) ssum += __expf(v[k] - mx);
            ssum += __shfl_xor(ssum, 1);
            float lg = mx + logf(ssum);
            float4 o0 = { v[0] - lg, v[1] - lg, v[2] - lg, v[3] - lg };
            float4 o1 = { v[4] - lg, v[5] - lg, v[6] - lg, v[7] - lg };
            out4[(size_t)node * 4 + h * 2 + 0] = o0;
            out4[(size_t)node * 4 + h * 2 + 1] = o1;
        }
    }
}

extern "C" void kernel_launch(void* const* d_in, const int* in_sizes, int n_in,
                              void* d_out, int out_size, void* d_ws, size_t ws_size,
                              hipStream_t stream) {
    const void* x  = d_in[0];
    const int*  ei = (const int*)d_in[1];
    const void* W1 = d_in[2];
    const void* b1 = d_in[3];
    const void* W2 = d_in[4];
    const void* b2 = d_in[5];

    const int n = in_sizes[0] / FEAT_IN;   // 100000
    const int e = in_sizes[1] / 2;         // 1600000
    const int NBk = (n + BUCK - 1) / BUCK; // 782 buckets of 128
    const int G = PART_G;                  // 192
    const int hlen = NBk * G;              // 150144 (<= 262144 scan limit)

    // workspace (16B-aligned blocks, no aliasing: part is read by both agg passes)
    int*   part  = (int*)d_ws;                             // e ints (6.4 MB)
    __hip_bfloat162* h1s2 = (__hip_bfloat162*)(part + e);  // 16n pairs (6.4 MB)
    __hip_bfloat162* h2s2 = h1s2 + 16 * (size_t)n;         // 8n pairs (3.2 MB)
    float* dinv  = (float*)(h2s2 + 8 * (size_t)n);         // n
    int* flags   = (int*)(dinv + n);                       // 4
    int* hist    = flags + 4;                              // hlen
    int* base    = hist + hlen;                            // hlen
    int* bsum    = base + hlen;                            // 256

    k_detect<<<1, 256, 0, stream>>>((const uint4*)x, ei, flags);

    k_hist<<<G, 256, 0, stream>>>(ei, e, flags, hist, G, NBk);
    int snb = (hlen + 1023) / 1024;  // 147
    k_scan1<<<snb, 256, 0, stream>>>(hist, base, bsum, hlen);
    k_scan2<<<1, 256, 0, stream>>>(bsum, snb);
    k_partition<<<G, 256, 0, stream>>>(ei, e, flags, base, bsum, part, G, NBk);
    k_bucket_dinv<<<NBk, 256, 0, stream>>>(part, base, bsum, e, G, NBk, n, dinv);

    k_gemm1<<<(n + 31) / 32, 256, 0, stream>>>(x, W1, flags, dinv, h1s2, n);
    k_agg1<<<NBk, 256, 0, stream>>>(part, base, bsum, e, G, NBk, n,
                                    (const uint4*)h1s2, W2, b1, flags, dinv, h2s2);
    k_agg2<<<NBk, 256, 0, stream>>>(part, base, bsum, e, G, NBk, n,
                                    (const uint4*)h2s2, b2, flags, dinv, (float4*)d_out);
}

// Round 8
// 197.671 us; speedup vs baseline: 3.3642x; 3.3642x over previous
//
#include <hip/hip_runtime.h>
#include <hip/hip_bf16.h>

// GCN 2-layer: h1 = relu(GCNConv(x, W1, b1)); out = log_softmax(GCNConv(h1, W2, b2))
// GCNConv(h)[d] = dinv[d] * ( sum_{s->d} (h@W)[s]*dinv[s] + (h@W)[d]*dinv[d] ) + b
//
// Round-8: r6 CSR-gather structure (known-good 214us) + bf16 intermediate
// tables (validated r7: absmax unchanged). r7's LDS-atomic aggregation is
// ABANDONED: 300k LDS bank conflicts, 8-deep same-bank atomic chains -> 665us.
// Dtypes (validated r0-r7): fp32 in/out, int32 edges; flags = runtime hedge.

#define FEAT_IN 64
#define FEAT_H  32
#define FEAT_O  16
#define MAXNB   512   // max buckets of 256 (n <= 131072; n < 2^24 for packing)
#define PART_G  192   // histogram/partition blocks

__device__ __forceinline__ float2 upk_bf2(unsigned w) {
    return make_float2(__uint_as_float(w << 16), __uint_as_float(w & 0xFFFF0000u));
}

__global__ void k_detect(const uint4* __restrict__ xw4,
                         const int* __restrict__ ei, int* __restrict__ flags) {
    __shared__ int s_f32, s_i64nz;
    if (threadIdx.x == 0) { s_f32 = 0; s_i64nz = 0; }
    __syncthreads();
    int t = threadIdx.x;
    int hit = 0;
    for (int i = t; i < 4096; i += 256) {
        uint4 u = xw4[i];
        unsigned a0 = u.x, a1 = u.y, a2 = u.z, a3 = u.w;
        if ((a0 & 0x7F800000u) == 0x7F800000u || (a0 & 0x00007F80u) == 0x00007F80u) hit = 1;
        if ((a1 & 0x7F800000u) == 0x7F800000u || (a1 & 0x00007F80u) == 0x00007F80u) hit = 1;
        if ((a2 & 0x7F800000u) == 0x7F800000u || (a2 & 0x00007F80u) == 0x00007F80u) hit = 1;
        if ((a3 & 0x7F800000u) == 0x7F800000u || (a3 & 0x00007F80u) == 0x00007F80u) hit = 1;
    }
    if (hit) atomicOr(&s_f32, 1);
    int nz = 0;
    for (int i = t; i < 128; i += 256) {
        if (ei[2 * i + 1] != 0) nz = 1;  // int32 edges: odd words random nonzero
    }
    if (nz) atomicOr(&s_i64nz, 1);
    __syncthreads();
    if (t == 0) { flags[0] = s_f32; flags[1] = s_i64nz ? 0 : 1; }
}

// ---- pass 1: per-block bucket histogram -> hist[b*G + g] ----
__global__ void k_hist(const int* __restrict__ ei, int e, const int* __restrict__ flags,
                       int* __restrict__ hist, int G, int NBk) {
    __shared__ int lh[MAXNB];
    int t = threadIdx.x, g = blockIdx.x;
    for (int i = t; i < NBk; i += 256) lh[i] = 0;
    __syncthreads();
    int chunk = (e + G - 1) / G;
    int beg = g * chunk, end = min(e, beg + chunk);
    bool i64 = flags[1] != 0;
    for (int i = beg + t; i < end; i += 256) {
        int d = i64 ? ei[2 * (e + i)] : ei[e + i];
        atomicAdd(&lh[d >> 8], 1);
    }
    __syncthreads();
    for (int i = t; i < NBk; i += 256) hist[(size_t)i * G + g] = lh[i];
}

// ---- exclusive scan (len <= 262144); final value = out[i] + bsum[i>>10] ----
__global__ void k_scan1(const int* __restrict__ in, int* __restrict__ out,
                        int* __restrict__ bsum, int len) {
    __shared__ int s[256];
    int t = threadIdx.x;
    int base = blockIdx.x * 1024 + t * 4;
    int a0 = (base + 0) < len ? in[base + 0] : 0;
    int a1 = (base + 1) < len ? in[base + 1] : 0;
    int a2 = (base + 2) < len ? in[base + 2] : 0;
    int a3 = (base + 3) < len ? in[base + 3] : 0;
    int tsum = a0 + a1 + a2 + a3;
    s[t] = tsum;
    __syncthreads();
    for (int off = 1; off < 256; off <<= 1) {
        int x = (t >= off) ? s[t - off] : 0;
        __syncthreads();
        s[t] += x;
        __syncthreads();
    }
    int ex = s[t] - tsum;
    if (base + 0 < len) out[base + 0] = ex;
    if (base + 1 < len) out[base + 1] = ex + a0;
    if (base + 2 < len) out[base + 2] = ex + a0 + a1;
    if (base + 3 < len) out[base + 3] = ex + a0 + a1 + a2;
    if (t == 255) bsum[blockIdx.x] = s[255];
}

__global__ void k_scan2(int* __restrict__ bsum, int nb) {  // nb <= 256
    __shared__ int s[256];
    int t = threadIdx.x;
    int v = (t < nb) ? bsum[t] : 0;
    s[t] = v;
    __syncthreads();
    for (int off = 1; off < 256; off <<= 1) {
        int x = (t >= off) ? s[t - off] : 0;
        __syncthreads();
        s[t] += x;
        __syncthreads();
    }
    if (t < nb) bsum[t] = s[t] - v;
}

__device__ __forceinline__ int base_at(const int* base, const int* bsum, int idx) {
    return base[idx] + bsum[idx >> 10];
}

// ---- pass 2: scatter packed (src | dlow<<24) into bucket-ordered part[] ----
__global__ void k_partition(const int* __restrict__ ei, int e, const int* __restrict__ flags,
                            const int* __restrict__ base, const int* __restrict__ bsum,
                            int* __restrict__ part, int G, int NBk) {
    __shared__ int cur[MAXNB];
    int t = threadIdx.x, g = blockIdx.x;
    for (int i = t; i < NBk; i += 256) cur[i] = base_at(base, bsum, i * G + g);
    __syncthreads();
    int chunk = (e + G - 1) / G;
    int beg = g * chunk, end = min(e, beg + chunk);
    bool i64 = flags[1] != 0;
    for (int i = beg + t; i < end; i += 256) {
        int s, d;
        if (i64) { s = ei[2 * i]; d = ei[2 * (e + i)]; }
        else     { s = ei[i];     d = ei[e + i]; }
        int pos = atomicAdd(&cur[d >> 8], 1);
        part[pos] = s | ((d & 255) << 24);   // n < 2^24
    }
}

// ---- pass 3: per-bucket CSR: LDS count -> scan -> row_start/dinv -> col fill ----
__global__ void k_bucket_csr(const int* __restrict__ part, const int* __restrict__ base,
                             const int* __restrict__ bsum, int e, int G, int NBk, int n,
                             int* __restrict__ row_start, int* __restrict__ col,
                             float* __restrict__ dinv) {
    __shared__ int cnt[256], spre[256], cur[256], ssc[256];
    int t = threadIdx.x, b = blockIdx.x;
    int beg = base_at(base, bsum, b * G);
    int end = (b == NBk - 1) ? e : base_at(base, bsum, (b + 1) * G);
    cnt[t] = 0; cur[t] = 0;
    __syncthreads();
    for (int j = beg + t; j < end; j += 256) atomicAdd(&cnt[((unsigned)part[j]) >> 24], 1);
    __syncthreads();
    int v = cnt[t];
    ssc[t] = v;
    __syncthreads();
    for (int off = 1; off < 256; off <<= 1) {
        int x = (t >= off) ? ssc[t - off] : 0;
        __syncthreads();
        ssc[t] += x;
        __syncthreads();
    }
    spre[t] = ssc[t] - v;  // exclusive prefix within bucket
    int node = b * 256 + t;
    if (node < n) {
        row_start[node] = beg + spre[t];
        dinv[node] = rsqrtf((float)v + 1.0f);  // +1 self-loop
    }
    if (b == NBk - 1 && t == 0) row_start[n] = e;
    __syncthreads();
    for (int j = beg + t; j < end; j += 256) {
        int r = part[j];
        int dl = ((unsigned)r) >> 24;
        int off = atomicAdd(&cur[dl], 1);
        col[beg + spre[dl] + off] = r & 0x00FFFFFF;
    }
}

// ---- layer 1 GEMM: h1s(bf16) = (x @ W1) * dinv ; 32 nodes/block ----
__global__ void k_gemm1(const void* __restrict__ xv, const void* __restrict__ W1v,
                        const int* __restrict__ flags, const float* __restrict__ dinv,
                        __hip_bfloat162* __restrict__ h1s2, int n) {
    __shared__ float sW[FEAT_IN * FEAT_H];   // 8 KB
    __shared__ float sx[16][FEAT_IN + 1];
    int t = threadIdx.x;
    bool f32 = flags[0] != 0;
    if (f32) {
        const float* W = (const float*)W1v;
        for (int i = t; i < FEAT_IN * FEAT_H; i += 256) sW[i] = W[i];
    } else {
        const __hip_bfloat16* W = (const __hip_bfloat16*)W1v;
        for (int i = t; i < FEAT_IN * FEAT_H; i += 256) sW[i] = __bfloat162float(W[i]);
    }
#pragma unroll
    for (int tile = 0; tile < 2; ++tile) {
        int nodeBase = blockIdx.x * 32 + tile * 16;
        __syncthreads();
        {   // stage 16 nodes of x
            int xn = t >> 4, c = t & 15;
            int node = nodeBase + xn;
            if (node < n) {
                if (f32) {
                    float4 v = ((const float4*)xv)[(size_t)node * 16 + c];
                    sx[xn][c * 4 + 0] = v.x; sx[xn][c * 4 + 1] = v.y;
                    sx[xn][c * 4 + 2] = v.z; sx[xn][c * 4 + 3] = v.w;
                } else {
                    const __hip_bfloat162* x2 = (const __hip_bfloat162*)xv;
                    float2 a = __bfloat1622float2(x2[(size_t)node * 32 + c * 2 + 0]);
                    float2 b = __bfloat1622float2(x2[(size_t)node * 32 + c * 2 + 1]);
                    sx[xn][c * 4 + 0] = a.x; sx[xn][c * 4 + 1] = a.y;
                    sx[xn][c * 4 + 2] = b.x; sx[xn][c * 4 + 3] = b.y;
                }
            }
        }
        __syncthreads();
        int nl = t >> 4, g = t & 15;
        int node = nodeBase + nl;
        if (node < n) {
            float a0 = 0.0f, a1 = 0.0f;
#pragma unroll
            for (int k = 0; k < FEAT_IN; ++k) {
                float s = sx[nl][k];
                a0 += s * sW[k * FEAT_H + 2 * g];
                a1 += s * sW[k * FEAT_H + 2 * g + 1];
            }
            float dv = dinv[node];
            __hip_bfloat162 o;
            o.x = __float2bfloat16(a0 * dv);
            o.y = __float2bfloat16(a1 * dv);
            h1s2[(size_t)node * 16 + g] = o;
        }
    }
}

// ---- gather layer1 (+relu+bias) fused with GEMM2: 64 nodes x 4 lanes ----
__global__ void k_gather1_gemm2(const int* __restrict__ row_start, const int* __restrict__ col,
                                const uint4* __restrict__ h1q, const void* __restrict__ W2v,
                                const void* __restrict__ b1v, const int* __restrict__ flags,
                                const float* __restrict__ dinv,
                                __hip_bfloat162* __restrict__ h2s2, int n) {
    __shared__ float sW[FEAT_H * FEAT_O];
    __shared__ float sb1[FEAT_H];
    __shared__ float sz[64][FEAT_H + 1];
    int t = threadIdx.x;
    bool f32 = flags[0] != 0;
    if (f32) {
        const float* W = (const float*)W2v;
        for (int i = t; i < FEAT_H * FEAT_O; i += 256) sW[i] = W[i];
        if (t < FEAT_H) sb1[t] = ((const float*)b1v)[t];
    } else {
        const __hip_bfloat16* W = (const __hip_bfloat16*)W2v;
        for (int i = t; i < FEAT_H * FEAT_O; i += 256) sW[i] = __bfloat162float(W[i]);
        if (t < FEAT_H) sb1[t] = __bfloat162float(((const __hip_bfloat16*)b1v)[t]);
    }
    __syncthreads();

    int g = t >> 2, l = t & 3;          // 64 nodes, 4 lanes each (16B bf16 = 8 feats)
    int d = blockIdx.x * 64 + g;
    if (d < n) {
        float a[8];
        {   // self-loop term
            uint4 u = h1q[(size_t)d * 4 + l];
            float2 p0 = upk_bf2(u.x), p1 = upk_bf2(u.y), p2 = upk_bf2(u.z), p3 = upk_bf2(u.w);
            a[0] = p0.x; a[1] = p0.y; a[2] = p1.x; a[3] = p1.y;
            a[4] = p2.x; a[5] = p2.y; a[6] = p3.x; a[7] = p3.y;
        }
        int beg = row_start[d], end = row_start[d + 1];
        int j = beg;
        for (; j + 4 <= end; j += 4) {   // 4 independent 16B gathers in flight
            int c0 = col[j + 0], c1 = col[j + 1], c2 = col[j + 2], c3 = col[j + 3];
            uint4 u0 = h1q[(size_t)c0 * 4 + l];
            uint4 u1 = h1q[(size_t)c1 * 4 + l];
            uint4 u2 = h1q[(size_t)c2 * 4 + l];
            uint4 u3 = h1q[(size_t)c3 * 4 + l];
            float2 p;
            p = upk_bf2(u0.x); a[0] += p.x; a[1] += p.y;
            p = upk_bf2(u0.y); a[2] += p.x; a[3] += p.y;
            p = upk_bf2(u0.z); a[4] += p.x; a[5] += p.y;
            p = upk_bf2(u0.w); a[6] += p.x; a[7] += p.y;
            p = upk_bf2(u1.x); a[0] += p.x; a[1] += p.y;
            p = upk_bf2(u1.y); a[2] += p.x; a[3] += p.y;
            p = upk_bf2(u1.z); a[4] += p.x; a[5] += p.y;
            p = upk_bf2(u1.w); a[6] += p.x; a[7] += p.y;
            p = upk_bf2(u2.x); a[0] += p.x; a[1] += p.y;
            p = upk_bf2(u2.y); a[2] += p.x; a[3] += p.y;
            p = upk_bf2(u2.z); a[4] += p.x; a[5] += p.y;
            p = upk_bf2(u2.w); a[6] += p.x; a[7] += p.y;
            p = upk_bf2(u3.x); a[0] += p.x; a[1] += p.y;
            p = upk_bf2(u3.y); a[2] += p.x; a[3] += p.y;
            p = upk_bf2(u3.z); a[4] += p.x; a[5] += p.y;
            p = upk_bf2(u3.w); a[6] += p.x; a[7] += p.y;
        }
        for (; j < end; ++j) {
            uint4 u = h1q[(size_t)col[j] * 4 + l];
            float2 p;
            p = upk_bf2(u.x); a[0] += p.x; a[1] += p.y;
            p = upk_bf2(u.y); a[2] += p.x; a[3] += p.y;
            p = upk_bf2(u.z); a[4] += p.x; a[5] += p.y;
            p = upk_bf2(u.w); a[6] += p.x; a[7] += p.y;
        }
        float dv = dinv[d];
#pragma unroll
        for (int k = 0; k < 8; ++k)
            sz[g][l * 8 + k] = fmaxf(dv * a[k] + sb1[l * 8 + k], 0.0f);
    }
    __syncthreads();
    // GEMM2: 64 nodes x 8 output-pairs = 512 items / 256 thr = 2 iters; bf16 store
#pragma unroll
    for (int it = 0; it < 2; ++it) {
        int nl = (t >> 3) + it * 32;
        int m = t & 7;
        int node = blockIdx.x * 64 + nl;
        if (node < n) {
            float a0 = 0.0f, a1 = 0.0f;
#pragma unroll
            for (int f = 0; f < FEAT_H; ++f) {
                float z = sz[nl][f];
                a0 += z * sW[f * FEAT_O + 2 * m];
                a1 += z * sW[f * FEAT_O + 2 * m + 1];
            }
            float dv = dinv[node];
            __hip_bfloat162 o;
            o.x = __float2bfloat16(a0 * dv);
            o.y = __float2bfloat16(a1 * dv);
            h2s2[(size_t)node * 8 + m] = o;
        }
    }
}

// ---- gather layer2 + bias + log_softmax: 128 nodes x 2 lanes ----
__global__ void k_gather2_lsm(const int* __restrict__ row_start, const int* __restrict__ col,
                              const uint4* __restrict__ h2q, const void* __restrict__ b2v,
                              const int* __restrict__ flags, const float* __restrict__ dinv,
                              float4* __restrict__ out4, int n) {
    __shared__ float sb2[FEAT_O];
    int t = threadIdx.x;
    if (t < FEAT_O) {
        sb2[t] = flags[0] ? ((const float*)b2v)[t]
                          : __bfloat162float(((const __hip_bfloat16*)b2v)[t]);
    }
    __syncthreads();
    int g = t >> 1, h = t & 1;          // 128 nodes, 2 lanes each (16B bf16 = 8 feats)
    int d = blockIdx.x * 128 + g;
    if (d >= n) return;
    float a[8];
    {
        uint4 u = h2q[(size_t)d * 2 + h];
        float2 p0 = upk_bf2(u.x), p1 = upk_bf2(u.y), p2 = upk_bf2(u.z), p3 = upk_bf2(u.w);
        a[0] = p0.x; a[1] = p0.y; a[2] = p1.x; a[3] = p1.y;
        a[4] = p2.x; a[5] = p2.y; a[6] = p3.x; a[7] = p3.y;
    }
    int beg = row_start[d], end = row_start[d + 1];
    int j = beg;
    for (; j + 4 <= end; j += 4) {
        int c0 = col[j + 0], c1 = col[j + 1], c2 = col[j + 2], c3 = col[j + 3];
        uint4 u0 = h2q[(size_t)c0 * 2 + h];
        uint4 u1 = h2q[(size_t)c1 * 2 + h];
        uint4 u2 = h2q[(size_t)c2 * 2 + h];
        uint4 u3 = h2q[(size_t)c3 * 2 + h];
        float2 p;
        p = upk_bf2(u0.x); a[0] += p.x; a[1] += p.y;
        p = upk_bf2(u0.y); a[2] += p.x; a[3] += p.y;
        p = upk_bf2(u0.z); a[4] += p.x; a[5] += p.y;
        p = upk_bf2(u0.w); a[6] += p.x; a[7] += p.y;
        p = upk_bf2(u1.x); a[0] += p.x; a[1] += p.y;
        p = upk_bf2(u1.y); a[2] += p.x; a[3] += p.y;
        p = upk_bf2(u1.z); a[4] += p.x; a[5] += p.y;
        p = upk_bf2(u1.w); a[6] += p.x; a[7] += p.y;
        p = upk_bf2(u2.x); a[0] += p.x; a[1] += p.y;
        p = upk_bf2(u2.y); a[2] += p.x; a[3] += p.y;
        p = upk_bf2(u2.z); a[4] += p.x; a[5] += p.y;
        p = upk_bf2(u2.w); a[6] += p.x; a[7] += p.y;
        p = upk_bf2(u3.x); a[0] += p.x; a[1] += p.y;
        p = upk_bf2(u3.y); a[2] += p.x; a[3] += p.y;
        p = upk_bf2(u3.z); a[4] += p.x; a[5] += p.y;
        p = upk_bf2(u3.w); a[6] += p.x; a[7] += p.y;
    }
    for (; j < end; ++j) {
        uint4 u = h2q[(size_t)col[j] * 2 + h];
        float2 p;
        p = upk_bf2(u.x); a[0] += p.x; a[1] += p.y;
        p = upk_bf2(u.y); a[2] += p.x; a[3] += p.y;
        p = upk_bf2(u.z); a[4] += p.x; a[5] += p.y;
        p = upk_bf2(u.w); a[6] += p.x; a[7] += p.y;
    }
    float dv = dinv[d];
    float v[8];
    float mx = -1e30f;
#pragma unroll
    for (int k = 0; k < 8; ++k) {
        v[k] = dv * a[k] + sb2[h * 8 + k];
        mx = fmaxf(mx, v[k]);
    }
    mx = fmaxf(mx, __shfl_xor(mx, 1));   // partner lane = same node, other half
    float ssum = 0.0f;
#pragma unroll
    for (int k = 0; k < 8; ++k) ssum += __expf(v[k] - mx);
    ssum += __shfl_xor(ssum, 1);
    float lg = mx + logf(ssum);
    float4 o0 = { v[0] - lg, v[1] - lg, v[2] - lg, v[3] - lg };
    float4 o1 = { v[4] - lg, v[5] - lg, v[6] - lg, v[7] - lg };
    out4[(size_t)d * 4 + h * 2 + 0] = o0;
    out4[(size_t)d * 4 + h * 2 + 1] = o1;
}

extern "C" void kernel_launch(void* const* d_in, const int* in_sizes, int n_in,
                              void* d_out, int out_size, void* d_ws, size_t ws_size,
                              hipStream_t stream) {
    const void* x  = d_in[0];
    const int*  ei = (const int*)d_in[1];
    const void* W1 = d_in[2];
    const void* b1 = d_in[3];
    const void* W2 = d_in[4];
    const void* b2 = d_in[5];

    const int n = in_sizes[0] / FEAT_IN;   // 100000
    const int e = in_sizes[1] / 2;         // 1600000
    const int NBk = (n + 255) >> 8;        // 391 buckets of 256
    const int G = PART_G;                  // 192
    const int hlen = NBk * G;              // 75072

    // workspace; part (4B*e = 6.4MB) aliased with h1s bf16 (32n*2B = 6.4MB):
    // bucket_csr fully consumes part before k_gemm1 writes h1s (stream-ordered)
    int* part = (int*)d_ws;                                   // e ints
    __hip_bfloat162* h1s2 = (__hip_bfloat162*)d_ws;           // 16n bf162, same region
    int* col  = (int*)d_ws + e;                               // e ints
    __hip_bfloat162* h2s2 = (__hip_bfloat162*)(col + e);      // 8n bf162 (3.2MB)
    float* dinv = (float*)(h2s2 + 8 * (size_t)n);             // n
    int* flags     = (int*)(dinv + n);                        // 4
    int* hist      = flags + 4;                               // hlen
    int* base      = hist + hlen;                             // hlen
    int* bsum      = base + hlen;                             // 256
    int* row_start = bsum + 256;                              // n+1

    k_detect<<<1, 256, 0, stream>>>((const uint4*)x, ei, flags);

    k_hist<<<G, 256, 0, stream>>>(ei, e, flags, hist, G, NBk);
    int snb = (hlen + 1023) / 1024;  // 74
    k_scan1<<<snb, 256, 0, stream>>>(hist, base, bsum, hlen);
    k_scan2<<<1, 256, 0, stream>>>(bsum, snb);
    k_partition<<<G, 256, 0, stream>>>(ei, e, flags, base, bsum, part, G, NBk);
    k_bucket_csr<<<NBk, 256, 0, stream>>>(part, base, bsum, e, G, NBk, n,
                                          row_start, col, dinv);

    k_gemm1<<<(n + 31) / 32, 256, 0, stream>>>(x, W1, flags, dinv, h1s2, n);
    k_gather1_gemm2<<<(n + 63) / 64, 256, 0, stream>>>(row_start, col, (const uint4*)h1s2,
                                                       W2, b1, flags, dinv, h2s2, n);
    k_gather2_lsm<<<(n + 127) / 128, 256, 0, stream>>>(row_start, col, (const uint4*)h2s2,
                                                       b2, flags, dinv, (float4*)d_out, n);
}